// Round 6
// baseline (192.917 us; speedup 1.0000x reference)
//
#include <hip/hip_runtime.h>

typedef unsigned long long u64;
typedef unsigned int u32;

#define G 512
#define T 128
#define P 256
#define B 512

// ---------------- workspace layout ----------------
// pv_ws  : B*4 u64   =  16 KB  (packed param_vals, linear bit order)
// psi_ws : G*T*4 u64 =   2 MB  (packed psi rows, word j = floats [64j,64j+64))
// phi_ws : G*T*4 u64 =   2 MB
#define PV_OFF    0
#define PSI_OFF   16384
#define PHI_OFF   (PSI_OFF + (size_t)G * T * 4 * 8)
#define WS_NEEDED (PHI_OFF + (size_t)G * T * 4 * 8)

// Linear bit order: bit k of word W <-> float (W*64 + k) of the flat array.
// Same permutation on matrices and param_vals -> AND-parity preserved.

#define PSI_WORDS (G * T * 4)            // 262144
#define PV_WORDS  (B * 4)                // 2048
#define WPB       512                    // words per block
#define CHUNKF    4096                   // floats per chunk (16 KB)
#define CHUNKS    (WPB * 64 / CHUNKF)    // 8
#define PACK_BLOCKS ((2 * PSI_WORDS + PV_WORDS) / WPB)   // 1028

// ---------------- pack via global_load_lds DMA ----------------
// Per chunk: 4 DMA insts/wave stage 16 KB fp32 into LDS (linear dest, linear
// src). Conversion: lane l reads ONE float at lane-stride-1 (conflict-free),
// __ballot(x!=0) yields a complete u64 word (word = r*4+wv, bit = lane).
// No VGPR load queue anywhere -> queue depth limited only by vmcnt.
__global__ __launch_bounds__(256) void pack_dma_kernel(
    const float* __restrict__ psi_params,
    const float* __restrict__ phi_params,
    const float* __restrict__ pv,
    u64* __restrict__ psi_ws,
    u64* __restrict__ phi_ws,
    u64* __restrict__ pv_ws)
{
    __shared__ __align__(16) float stage[CHUNKF];   // 16 KB -> 8 blocks/CU

    const int lane = threadIdx.x & 63;
    const int wv   = threadIdx.x >> 6;
    const int blk  = blockIdx.x;

    const float* src;
    u64*         dst;
    if (blk < 512) {
        src = psi_params + (size_t)blk * WPB * 64;
        dst = psi_ws + (size_t)blk * WPB;
    } else if (blk < 1024) {
        src = phi_params + (size_t)(blk - 512) * WPB * 64;
        dst = phi_ws + (size_t)(blk - 512) * WPB;
    } else {
        src = pv + (size_t)(blk - 1024) * WPB * 64;
        dst = pv_ws + (size_t)(blk - 1024) * WPB;
    }

    for (int c = 0; c < CHUNKS; ++c) {
        // ---- DMA 16 KB: wave wv covers floats [wv*1024, wv*1024+1024) ----
        const float* s0 = src + (size_t)c * CHUNKF + wv * 1024;
        #pragma unroll
        for (int k = 0; k < 4; ++k) {
            __builtin_amdgcn_global_load_lds(
                (const __attribute__((address_space(1))) u32*)(s0 + k * 256 + lane * 4),
                (__attribute__((address_space(3))) u32*)&stage[wv * 1024 + k * 256],
                16, 0, 0);
        }
        asm volatile("s_waitcnt vmcnt(0)" ::: "memory");
        __syncthreads();

        // ---- convert: 16 ballots -> 16 u64 words per wave ----
        u64 myw = 0;
        #pragma unroll
        for (int r = 0; r < 16; ++r) {
            float x = stage[r * 256 + wv * 64 + lane];   // lane-stride 1: free
            u64 bal = __ballot(x != 0.0f);               // word r*4+wv, bit=lane
            if (lane == r) myw = bal;
        }
        if (lane < 16) dst[c * 64 + lane * 4 + wv] = myw;
        __syncthreads();   // protect stage before next chunk's DMA
    }
}

// ---------------- compute pass (round-3 verified pi_trans) ----------------
// Block = graph g, 512 threads. Lane l owns terms t=l, t=l+64 (32 VGPRs,
// coalesced load). Loop over b with SGPR-uniform pv masks; 32 b-results
// bit-packed per lane; 6-step XOR shuffle-reduce; coalesced epilogue.
__global__ __launch_bounds__(512) void pi_trans_kernel(
    const int*      __restrict__ psi_const,
    const int*      __restrict__ phi_const,
    const u64*      __restrict__ psi_ws,
    const u64*      __restrict__ phi_ws,
    const u64*      __restrict__ pv,
    float4*         __restrict__ out)
{
    const int g    = blockIdx.x;
    const int lane = threadIdx.x & 63;
    const int wv   = threadIdx.x >> 6;

    u64 ra[8], rb[8];   // ra: psi[0..3], phi[4..7] for t=lane; rb: t=lane+64
    {
        const ulonglong2* pA0 = (const ulonglong2*)(psi_ws + ((size_t)g * T + lane) * 4);
        const ulonglong2* pB0 = (const ulonglong2*)(phi_ws + ((size_t)g * T + lane) * 4);
        const ulonglong2* pA1 = (const ulonglong2*)(psi_ws + ((size_t)g * T + lane + 64) * 4);
        const ulonglong2* pB1 = (const ulonglong2*)(phi_ws + ((size_t)g * T + lane + 64) * 4);
        ulonglong2 x;
        x = pA0[0]; ra[0] = x.x; ra[1] = x.y;
        x = pA0[1]; ra[2] = x.x; ra[3] = x.y;
        x = pB0[0]; ra[4] = x.x; ra[5] = x.y;
        x = pB0[1]; ra[6] = x.x; ra[7] = x.y;
        x = pA1[0]; rb[0] = x.x; rb[1] = x.y;
        x = pA1[1]; rb[2] = x.x; rb[3] = x.y;
        x = pB1[0]; rb[4] = x.x; rb[5] = x.y;
        x = pB1[1]; rb[6] = x.x; rb[7] = x.y;
    }
    unsigned pa = ((unsigned)psi_const[g * T + lane]) & 1u;
    unsigned qa = ((unsigned)phi_const[g * T + lane]) & 1u;
    unsigned pb = ((unsigned)psi_const[g * T + lane + 64]) & 1u;
    unsigned qb = ((unsigned)phi_const[g * T + lane + 64]) & 1u;

    #pragma unroll
    for (int grp = 0; grp < 2; ++grp) {
        int b0  = wv * 64 + grp * 32;
        int b0u = __builtin_amdgcn_readfirstlane(b0);   // SGPR base -> s_load
        const u64* vp = pv + (size_t)b0u * 4;

        unsigned acc = 0;
        #pragma unroll
        for (int i = 0; i < 32; ++i) {
            u64 v0 = vp[i * 4 + 0], v1 = vp[i * 4 + 1];
            u64 v2 = vp[i * 4 + 2], v3 = vp[i * 4 + 3];
            u64 m0 = (ra[0] & v0) ^ (ra[1] & v1) ^ (ra[2] & v2) ^ (ra[3] & v3);
            u64 m1 = (ra[4] & v0) ^ (ra[5] & v1) ^ (ra[6] & v2) ^ (ra[7] & v3);
            u64 m2 = (rb[0] & v0) ^ (rb[1] & v1) ^ (rb[2] & v2) ^ (rb[3] & v3);
            u64 m3 = (rb[4] & v0) ^ (rb[5] & v1) ^ (rb[6] & v2) ^ (rb[7] & v3);
            unsigned f0 = (unsigned)m0 ^ (unsigned)(m0 >> 32);
            unsigned f1 = (unsigned)m1 ^ (unsigned)(m1 >> 32);
            unsigned f2 = (unsigned)m2 ^ (unsigned)(m2 >> 32);
            unsigned f3 = (unsigned)m3 ^ (unsigned)(m3 >> 32);
            unsigned t01 = ((unsigned)__popc(f0) ^ pa) & ((unsigned)__popc(f1) ^ qa);
            unsigned t23 = ((unsigned)__popc(f2) ^ pb) & ((unsigned)__popc(f3) ^ qb);
            acc ^= ((t01 ^ t23) & 1u) << i;
        }

        unsigned red = acc;
        #pragma unroll
        for (int m = 1; m < 64; m <<= 1)
            red ^= __shfl_xor(red, m, 64);

        if (lane < 32) {
            int b = b0u + lane;
            float s = 1.0f - 2.0f * (float)((red >> lane) & 1u);
            out[(size_t)b * G + g] = make_float4(s, 0.0f, 0.0f, 0.0f);
        }
    }
}

// ---------------- fallback path (round-0 verified kernels) ----------------
struct __align__(16) U64x2 { u64 x, y; };

__global__ __launch_bounds__(256) void pack_pv_kernel(
    const float* __restrict__ pv, u64* __restrict__ out)
{
    int lane = threadIdx.x & 63;
    int wave = threadIdx.x >> 6;
    int row  = blockIdx.x * 4 + wave;
    const float4* src = (const float4*)(pv + (size_t)row * P);
    float4 f = src[lane];
    u64 w0 = __ballot(f.x != 0.0f);
    u64 w1 = __ballot(f.y != 0.0f);
    u64 w2 = __ballot(f.z != 0.0f);
    u64 w3 = __ballot(f.w != 0.0f);
    if (lane == 0) {
        out[row * 4 + 0] = w0;
        out[row * 4 + 1] = w1;
        out[row * 4 + 2] = w2;
        out[row * 4 + 3] = w3;
    }
}

__global__ __launch_bounds__(512) void pi_main_kernel(
    const int*   __restrict__ psi_const,
    const float* __restrict__ psi_params,
    const int*   __restrict__ phi_const,
    const float* __restrict__ phi_params,
    const u64*   __restrict__ pv,
    float4*      __restrict__ out)
{
    __shared__ __align__(16) u64 rows[T * 8];
    __shared__ unsigned code_sm[T];

    const int g    = blockIdx.x;
    const int tid  = threadIdx.x;
    const int lane = tid & 63;
    const int wave = tid >> 6;

    if (tid < T) {
        unsigned pc = ((unsigned)psi_const[g * T + tid]) & 1u;
        unsigned qc = ((unsigned)phi_const[g * T + tid]) & 1u;
        code_sm[tid] = pc | (qc << 1);
    }

    for (int i = 0; i < 32; ++i) {
        int r = wave * 32 + i;
        int t = r & (T - 1);
        const float* mat = (r < T) ? psi_params : phi_params;
        int off = (r < T) ? 0 : 4;
        const float4* src = (const float4*)(mat + ((size_t)g * T + t) * P);
        float4 f = src[lane];
        u64 w0 = __ballot(f.x != 0.0f);
        u64 w1 = __ballot(f.y != 0.0f);
        u64 w2 = __ballot(f.z != 0.0f);
        u64 w3 = __ballot(f.w != 0.0f);
        if (lane == 0) {
            U64x2* d = (U64x2*)&rows[t * 8 + off];
            U64x2 a; a.x = w0; a.y = w1;
            U64x2 c; c.x = w2; c.y = w3;
            d[0] = a;
            d[1] = c;
        }
    }
    __syncthreads();

    const int b = tid;
    const u64* v = pv + (size_t)b * 4;
    u64 v0 = v[0], v1 = v[1], v2 = v[2], v3 = v[3];

    unsigned e = 0;
    #pragma unroll 8
    for (int t = 0; t < T; ++t) {
        const U64x2* row = (const U64x2*)&rows[t * 8];
        U64x2 p0 = row[0], p1 = row[1], q0 = row[2], q1 = row[3];
        u64 ma = (p0.x & v0) ^ (p0.y & v1) ^ (p1.x & v2) ^ (p1.y & v3);
        u64 mb = (q0.x & v0) ^ (q0.y & v1) ^ (q1.x & v2) ^ (q1.y & v3);
        unsigned c = code_sm[t];
        e ^= (((unsigned)__popcll(ma) ^ c) & ((unsigned)__popcll(mb) ^ (c >> 1)));
    }
    e &= 1u;

    float s = 1.0f - 2.0f * (float)e;
    out[(size_t)b * G + g] = make_float4(s, 0.0f, 0.0f, 0.0f);
}

// ---------------- launch ----------------
extern "C" void kernel_launch(void* const* d_in, const int* in_sizes, int n_in,
                              void* d_out, int out_size, void* d_ws, size_t ws_size,
                              hipStream_t stream) {
    const int*   psi_const  = (const int*)  d_in[0];
    const float* psi_params = (const float*)d_in[1];
    const int*   phi_const  = (const int*)  d_in[2];
    const float* phi_params = (const float*)d_in[3];
    const float* param_vals = (const float*)d_in[4];

    if (ws_size >= WS_NEEDED) {
        u64* pv_ws  = (u64*)((char*)d_ws + PV_OFF);
        u64* psi_ws = (u64*)((char*)d_ws + PSI_OFF);
        u64* phi_ws = (u64*)((char*)d_ws + PHI_OFF);

        pack_dma_kernel<<<PACK_BLOCKS, 256, 0, stream>>>(
            psi_params, phi_params, param_vals, psi_ws, phi_ws, pv_ws);
        pi_trans_kernel<<<G, 512, 0, stream>>>(
            psi_const, phi_const, psi_ws, phi_ws, pv_ws, (float4*)d_out);
    } else {
        u64* pv_packed = (u64*)d_ws;
        pack_pv_kernel<<<B / 4, 256, 0, stream>>>(param_vals, pv_packed);
        pi_main_kernel<<<G, 512, 0, stream>>>(psi_const, psi_params,
                                              phi_const, phi_params,
                                              pv_packed, (float4*)d_out);
    }
}

// Round 7
// 172.031 us; speedup vs baseline: 1.1214x; 1.1214x over previous
//
#include <hip/hip_runtime.h>

typedef unsigned long long u64;
typedef unsigned int u32;

#define G 512
#define T 128
#define P 256
#define B 512

// ---------------- workspace layout ----------------
// pv_ws  : B*4 u64   = 16 KB  (packed param_vals, linear bit order)
// par_ws : G*16 u32  = 32 KB  (parity bits, [g][b>>5], bit = b&31)
#define PV_OFF    0
#define PAR_OFF   16384
#define WS_NEEDED (PAR_OFF + (size_t)G * 16 * 4)

// Linear bit order: bit k of word W <-> float (W*64 + k) of the flat array.
// Same permutation on matrices and param_vals -> AND-parity preserved.

__device__ __forceinline__ unsigned nzbit(unsigned u) {
    return (u | (0u - u)) >> 31;   // 1 iff u != 0
}

__device__ __forceinline__ u64 pack64(const uint4* sv) {
    uint4 f[16];
    #pragma unroll
    for (int i = 0; i < 16; ++i) f[i] = sv[i];
    __builtin_amdgcn_sched_barrier(0);
    unsigned lo = 0, hi = 0;
    #pragma unroll
    for (int i = 0; i < 8; ++i) {
        lo |= nzbit(f[i].x) << (4 * i + 0);
        lo |= nzbit(f[i].y) << (4 * i + 1);
        lo |= nzbit(f[i].z) << (4 * i + 2);
        lo |= nzbit(f[i].w) << (4 * i + 3);
    }
    #pragma unroll
    for (int i = 8; i < 16; ++i) {
        hi |= nzbit(f[i].x) << (4 * (i - 8) + 0);
        hi |= nzbit(f[i].y) << (4 * (i - 8) + 1);
        hi |= nzbit(f[i].z) << (4 * (i - 8) + 2);
        hi |= nzbit(f[i].w) << (4 * (i - 8) + 3);
    }
    return ((u64)hi << 32) | (u64)lo;
}

// ---------------- k1: pack pv + zero parity workspace (R5-verified) --------
__global__ __launch_bounds__(256) void pack_pv_zero_kernel(
    const float* __restrict__ pv, u64* __restrict__ pv_ws,
    uint4* __restrict__ par_zero)
{
    int tid = blockIdx.x * 256 + threadIdx.x;            // 0..2047
    pv_ws[tid] = pack64((const uint4*)(pv + (size_t)tid * 64));
    par_zero[tid] = make_uint4(0, 0, 0, 0);              // 2048*16B = 32 KB
}

// ---------------- k2: fine-grained fused pack+compute ----------------
// One SINGLE-WAVE block per (graph g, 4-term group): 16384 blocks of 64.
// DMA 8 KB fp32 (4 psi rows + 4 phi rows) -> LDS; vmcnt(0) (no barrier,
// single wave); 32 ballots convert to 32 wave-uniform packed u64 in VGPRs;
// b-loop: lane = b within 64-b chunk, pv masks coalesced from L2-hot table;
// per-chunk parity bit ballot-packed; 16 atomicXor merge the group into
// par_ws (XOR over term-groups is order-free -> no dispatch-order hazard).
#define GRP 4
#define NGRP (T / GRP)                  // 32
#define MAIN_BLOCKS (G * NGRP)          // 16384

__global__ __launch_bounds__(64, 4) void pi_group_kernel(
    const int*   __restrict__ psi_const,
    const int*   __restrict__ phi_const,
    const float* __restrict__ psi_params,
    const float* __restrict__ phi_params,
    const u64*   __restrict__ pv_ws,
    unsigned*    __restrict__ par_ws)
{
    __shared__ __align__(16) float stage[2 * GRP * 256];   // 8 KB

    const int lane = threadIdx.x;           // single wave
    const int g    = blockIdx.x >> 5;
    const int grp  = blockIdx.x & (NGRP - 1);

    const float* ps = psi_params + ((size_t)g * T + grp * GRP) * P;
    const float* qs = phi_params + ((size_t)g * T + grp * GRP) * P;

    // ---- DMA 8 KB: 8 x (64 lanes x 16 B), linear dest + linear src ----
    #pragma unroll
    for (int k = 0; k < 4; ++k) {
        __builtin_amdgcn_global_load_lds(
            (const __attribute__((address_space(1))) u32*)(ps + k * 256 + lane * 4),
            (__attribute__((address_space(3))) u32*)&stage[k * 256],
            16, 0, 0);
    }
    #pragma unroll
    for (int k = 0; k < 4; ++k) {
        __builtin_amdgcn_global_load_lds(
            (const __attribute__((address_space(1))) u32*)(qs + k * 256 + lane * 4),
            (__attribute__((address_space(3))) u32*)&stage[1024 + k * 256],
            16, 0, 0);
    }
    asm volatile("s_waitcnt vmcnt(0)" ::: "memory");

    // ---- convert: 32 ballots -> 32 wave-uniform packed u64 in VGPRs ----
    u64 ra[GRP][8];    // [t][0..3]=psi words, [4..7]=phi words
    #pragma unroll
    for (int t = 0; t < GRP; ++t) {
        #pragma unroll
        for (int j = 0; j < 4; ++j) {
            float xp = stage[t * 256 + j * 64 + lane];          // stride-1: free
            ra[t][j]     = __ballot(xp != 0.0f);
            float xq = stage[1024 + t * 256 + j * 64 + lane];
            ra[t][4 + j] = __ballot(xq != 0.0f);
        }
    }

    unsigned pa[GRP], qa[GRP];
    #pragma unroll
    for (int t = 0; t < GRP; ++t) {
        pa[t] = ((unsigned)psi_const[g * T + grp * GRP + t]) & 1u;
        qa[t] = ((unsigned)phi_const[g * T + grp * GRP + t]) & 1u;
    }

    // ---- b-loop: 8 chunks of 64 b, lane = b within chunk ----
    unsigned wacc = 0;
    #pragma unroll
    for (int c = 0; c < 8; ++c) {
        const ulonglong2* vp =
            (const ulonglong2*)(pv_ws + ((size_t)(c * 64) + lane) * 4);
        ulonglong2 ua = vp[0], ub = vp[1];
        u64 v0 = ua.x, v1 = ua.y, v2 = ub.x, v3 = ub.y;

        unsigned e = 0;
        #pragma unroll
        for (int t = 0; t < GRP; ++t) {
            u64 m0 = (ra[t][0] & v0) ^ (ra[t][1] & v1)
                   ^ (ra[t][2] & v2) ^ (ra[t][3] & v3);
            u64 m1 = (ra[t][4] & v0) ^ (ra[t][5] & v1)
                   ^ (ra[t][6] & v2) ^ (ra[t][7] & v3);
            e ^= (((unsigned)__popcll(m0) ^ pa[t])
                & ((unsigned)__popcll(m1) ^ qa[t]));
        }

        u64 bal = __ballot(e & 1u);     // bit l = parity of b = c*64 + l
        if (lane == 2 * c)     wacc = (unsigned)bal;
        if (lane == 2 * c + 1) wacc = (unsigned)(bal >> 32);
    }

    if (lane < 16) atomicXor(&par_ws[g * 16 + lane], wacc);
}

// ---------------- k3: epilogue (R5-verified), coalesced sign stores --------
__global__ __launch_bounds__(256) void epilogue_kernel(
    const unsigned* __restrict__ par_ws, float4* __restrict__ out)
{
    int id = blockIdx.x * 256 + threadIdx.x;     // 0..262143 = b*512 + g
    int b  = id >> 9;
    int gg = id & 511;
    unsigned w = par_ws[gg * 16 + (b >> 5)];
    float s = 1.0f - 2.0f * (float)((w >> (b & 31)) & 1u);
    out[id] = make_float4(s, 0.0f, 0.0f, 0.0f);
}

// ---------------- fallback path (round-0 verified kernels) ----------------
struct __align__(16) U64x2 { u64 x, y; };

__global__ __launch_bounds__(256) void pack_pv_kernel(
    const float* __restrict__ pv, u64* __restrict__ out)
{
    int lane = threadIdx.x & 63;
    int wave = threadIdx.x >> 6;
    int row  = blockIdx.x * 4 + wave;
    const float4* src = (const float4*)(pv + (size_t)row * P);
    float4 f = src[lane];
    u64 w0 = __ballot(f.x != 0.0f);
    u64 w1 = __ballot(f.y != 0.0f);
    u64 w2 = __ballot(f.z != 0.0f);
    u64 w3 = __ballot(f.w != 0.0f);
    if (lane == 0) {
        out[row * 4 + 0] = w0;
        out[row * 4 + 1] = w1;
        out[row * 4 + 2] = w2;
        out[row * 4 + 3] = w3;
    }
}

__global__ __launch_bounds__(512) void pi_main_kernel(
    const int*   __restrict__ psi_const,
    const float* __restrict__ psi_params,
    const int*   __restrict__ phi_const,
    const float* __restrict__ phi_params,
    const u64*   __restrict__ pv,
    float4*      __restrict__ out)
{
    __shared__ __align__(16) u64 rows[T * 8];
    __shared__ unsigned code_sm[T];

    const int g    = blockIdx.x;
    const int tid  = threadIdx.x;
    const int lane = tid & 63;
    const int wave = tid >> 6;

    if (tid < T) {
        unsigned pc = ((unsigned)psi_const[g * T + tid]) & 1u;
        unsigned qc = ((unsigned)phi_const[g * T + tid]) & 1u;
        code_sm[tid] = pc | (qc << 1);
    }

    for (int i = 0; i < 32; ++i) {
        int r = wave * 32 + i;
        int t = r & (T - 1);
        const float* mat = (r < T) ? psi_params : phi_params;
        int off = (r < T) ? 0 : 4;
        const float4* src = (const float4*)(mat + ((size_t)g * T + t) * P);
        float4 f = src[lane];
        u64 w0 = __ballot(f.x != 0.0f);
        u64 w1 = __ballot(f.y != 0.0f);
        u64 w2 = __ballot(f.z != 0.0f);
        u64 w3 = __ballot(f.w != 0.0f);
        if (lane == 0) {
            U64x2* d = (U64x2*)&rows[t * 8 + off];
            U64x2 a; a.x = w0; a.y = w1;
            U64x2 c; c.x = w2; c.y = w3;
            d[0] = a;
            d[1] = c;
        }
    }
    __syncthreads();

    const int b = tid;
    const u64* v = pv + (size_t)b * 4;
    u64 v0 = v[0], v1 = v[1], v2 = v[2], v3 = v[3];

    unsigned e = 0;
    #pragma unroll 8
    for (int t = 0; t < T; ++t) {
        const U64x2* row = (const U64x2*)&rows[t * 8];
        U64x2 p0 = row[0], p1 = row[1], q0 = row[2], q1 = row[3];
        u64 ma = (p0.x & v0) ^ (p0.y & v1) ^ (p1.x & v2) ^ (p1.y & v3);
        u64 mb = (q0.x & v0) ^ (q0.y & v1) ^ (q1.x & v2) ^ (q1.y & v3);
        unsigned c = code_sm[t];
        e ^= (((unsigned)__popcll(ma) ^ c) & ((unsigned)__popcll(mb) ^ (c >> 1)));
    }
    e &= 1u;

    float s = 1.0f - 2.0f * (float)e;
    out[(size_t)b * G + g] = make_float4(s, 0.0f, 0.0f, 0.0f);
}

// ---------------- launch ----------------
extern "C" void kernel_launch(void* const* d_in, const int* in_sizes, int n_in,
                              void* d_out, int out_size, void* d_ws, size_t ws_size,
                              hipStream_t stream) {
    const int*   psi_const  = (const int*)  d_in[0];
    const float* psi_params = (const float*)d_in[1];
    const int*   phi_const  = (const int*)  d_in[2];
    const float* phi_params = (const float*)d_in[3];
    const float* param_vals = (const float*)d_in[4];

    if (ws_size >= WS_NEEDED) {
        u64*      pv_ws  = (u64*)((char*)d_ws + PV_OFF);
        unsigned* par_ws = (unsigned*)((char*)d_ws + PAR_OFF);

        pack_pv_zero_kernel<<<8, 256, 0, stream>>>(
            param_vals, pv_ws, (uint4*)par_ws);
        pi_group_kernel<<<MAIN_BLOCKS, 64, 0, stream>>>(
            psi_const, phi_const, psi_params, phi_params, pv_ws, par_ws);
        epilogue_kernel<<<(B * G) / 256, 256, 0, stream>>>(
            par_ws, (float4*)d_out);
    } else {
        u64* pv_packed = (u64*)d_ws;
        pack_pv_kernel<<<B / 4, 256, 0, stream>>>(param_vals, pv_packed);
        pi_main_kernel<<<G, 512, 0, stream>>>(psi_const, psi_params,
                                              phi_const, phi_params,
                                              pv_packed, (float4*)d_out);
    }
}